// Round 1
// baseline (925.745 us; speedup 1.0000x reference)
//
#include <hip/hip_runtime.h>
#include <math.h>

#define N_EDGES 4096
#define NN1 256
#define NN2 128

// ---------------- reduction helpers ----------------
template<int NT>
__device__ inline float block_sum(float v, float* red, int t){
  red[t] = v; __syncthreads();
  #pragma unroll
  for (int st = NT/2; st > 0; st >>= 1){
    if (t < st) red[t] += red[t+st];
    __syncthreads();
  }
  float r = red[0]; __syncthreads();
  return r;
}
template<int NT>
__device__ inline float block_max(float v, float* red, int t){
  red[t] = v; __syncthreads();
  #pragma unroll
  for (int st = NT/2; st > 0; st >>= 1){
    if (t < st) red[t] = fmaxf(red[t], red[t+st]);
    __syncthreads();
  }
  float r = red[0]; __syncthreads();
  return r;
}
template<int NT>
__device__ inline int block_min_int(int v, int* red, int t){
  red[t] = v; __syncthreads();
  #pragma unroll
  for (int st = NT/2; st > 0; st >>= 1){
    if (t < st) red[t] = min(red[t], red[t+st]);
    __syncthreads();
  }
  int r = red[0]; __syncthreads();
  return r;
}

// ---------------- fused conv3x3(SAME) + ReLU + maxpool2x2 ----------------
// in: [CIN,H,W]  w: [COUT,CIN,3,3]  b: [COUT]  out: [COUT,H/2,W/2]
// block = 256 threads = 64 spatial (8x8 pool outputs) x 4 output channels
// grid = (W/16, H/16, COUT/4)
template<int CIN>
__global__ __launch_bounds__(256) void conv_relu_pool(
    const float* __restrict__ in, const float* __restrict__ w,
    const float* __restrict__ bias, float* __restrict__ out,
    int H, int W)
{
  constexpr int CHUNK = (CIN < 8) ? CIN : 8;
  __shared__ float tile[CHUNK][18][18];
  const int OW = W >> 1;
  const int tx0 = blockIdx.x * 8;
  const int ty0 = blockIdx.y * 8;
  const int cout = blockIdx.z * 4 + (threadIdx.x & 3);
  const int sp = threadIdx.x >> 2;       // 0..63
  const int px = sp & 7, py = sp >> 3;   // pool coords inside tile
  const int iy0 = 2*ty0 - 1, ix0 = 2*tx0 - 1;
  float a00=0.f, a01=0.f, a10=0.f, a11=0.f;

  for (int c0 = 0; c0 < CIN; c0 += CHUNK){
    __syncthreads();
    for (int e = threadIdx.x; e < CHUNK*324; e += 256){
      int c  = e / 324;
      int r  = e - c*324;
      int rr = r / 18;
      int cc = r - rr*18;
      int yy = iy0 + rr, xx = ix0 + cc;
      float v = 0.f;
      if (yy >= 0 && yy < H && xx >= 0 && xx < W)
        v = in[(size_t)(c0+c)*H*W + (size_t)yy*W + xx];
      tile[c][rr][cc] = v;
    }
    __syncthreads();
    const int ry = 2*py, rx = 2*px;
    #pragma unroll
    for (int c = 0; c < CHUNK; ++c){
      const float* wp = w + ((size_t)cout*CIN + (c0+c))*9;
      float w0=wp[0],w1=wp[1],w2=wp[2],w3=wp[3],w4=wp[4],w5=wp[5],w6=wp[6],w7=wp[7],w8=wp[8];
      float p00=tile[c][ry+0][rx+0], p01=tile[c][ry+0][rx+1], p02=tile[c][ry+0][rx+2], p03=tile[c][ry+0][rx+3];
      float p10=tile[c][ry+1][rx+0], p11=tile[c][ry+1][rx+1], p12=tile[c][ry+1][rx+2], p13=tile[c][ry+1][rx+3];
      float p20=tile[c][ry+2][rx+0], p21=tile[c][ry+2][rx+1], p22=tile[c][ry+2][rx+2], p23=tile[c][ry+2][rx+3];
      float p30=tile[c][ry+3][rx+0], p31=tile[c][ry+3][rx+1], p32=tile[c][ry+3][rx+2], p33=tile[c][ry+3][rx+3];
      a00 += w0*p00+w1*p01+w2*p02 + w3*p10+w4*p11+w5*p12 + w6*p20+w7*p21+w8*p22;
      a01 += w0*p01+w1*p02+w2*p03 + w3*p11+w4*p12+w5*p13 + w6*p21+w7*p22+w8*p23;
      a10 += w0*p10+w1*p11+w2*p12 + w3*p20+w4*p21+w5*p22 + w6*p30+w7*p31+w8*p32;
      a11 += w0*p11+w1*p12+w2*p13 + w3*p21+w4*p22+w5*p23 + w6*p31+w7*p32+w8*p33;
    }
  }
  float m = fmaxf(fmaxf(a00,a01), fmaxf(a10,a11)) + bias[cout];
  out[(size_t)cout*(H>>1)*OW + (size_t)(ty0+py)*OW + (tx0+px)] = fmaxf(m, 0.f);
}

// ---------------- graph kernels ----------------
__global__ void build_adj_kernel(const int* __restrict__ ei, float* adj, float* cnt){
  int e = blockIdx.x*256 + threadIdx.x;
  if (e < N_EDGES){
    int s = ei[e], d = ei[N_EDGES + e];
    atomicAdd(&adj[s*NN1 + d], 1.0f);   // integer-valued -> order independent
    atomicAdd(&cnt[d], 1.0f);
  }
}

// aggn[d][j] = (sum_s adj[s][d]*org[s][j]) / max(cnt[d],1)
__global__ __launch_bounds__(256) void agg_kernel(const float* __restrict__ adj,
    const float* __restrict__ cnt, const float* __restrict__ org, float* __restrict__ aggn){
  int d = blockIdx.x, j = threadIdx.x;
  float acc = 0.f;
  for (int s = 0; s < NN1; ++s){
    float a = adj[s*NN1 + d];
    if (a != 0.f) acc += a * org[s*NN1 + j];   // uniform branch: a same across block
  }
  aggn[d*NN1 + j] = acc / fmaxf(cnt[d], 1.0f);
}

// both SAGE heads share aggn; x1 = L2norm(lin), s = softmax(L2norm(lin2)); ent partials
__global__ __launch_bounds__(128) void sage12_kernel(
    const float* __restrict__ aggn, const float* __restrict__ org,
    const float* __restrict__ wl1, const float* __restrict__ bl1, const float* __restrict__ wr1,
    const float* __restrict__ wl2, const float* __restrict__ bl2, const float* __restrict__ wr2,
    float* __restrict__ x1, float* __restrict__ s_out, float* __restrict__ entpart)
{
  __shared__ float sa[NN1], so[NN1], red[128];
  int n = blockIdx.x, c = threadIdx.x;
  for (int k = c; k < NN1; k += 128){ sa[k] = aggn[n*NN1+k]; so[k] = org[n*NN1+k]; }
  __syncthreads();
  float p1 = bl1[c], p2 = bl2[c];
  const float* wl1r = wl1 + c*NN1; const float* wr1r = wr1 + c*NN1;
  const float* wl2r = wl2 + c*NN1; const float* wr2r = wr2 + c*NN1;
  for (int k = 0; k < NN1; ++k){
    float av = sa[k], ov = so[k];
    p1 += av*wl1r[k] + ov*wr1r[k];
    p2 += av*wl2r[k] + ov*wr2r[k];
  }
  float n1s = block_sum<128>(p1*p1, red, c);
  x1[n*128 + c] = p1 / fmaxf(sqrtf(n1s), 1e-12f);
  float n2s = block_sum<128>(p2*p2, red, c);
  float p2n = p2 / fmaxf(sqrtf(n2s), 1e-12f);
  float mx = block_max<128>(p2n, red, c);
  float ev = expf(p2n - mx);
  float ssum = block_sum<128>(ev, red, c);
  float sv = ev / ssum;
  s_out[n*128 + c] = sv;
  float esum = block_sum<128>(-sv * logf(sv + 1e-15f), red, c);
  if (c == 0) entpart[n] = esum;
}

// xp[c][f] = sum_n s[n][c]*x1[n][f]
__global__ __launch_bounds__(128) void xp_kernel(const float* __restrict__ s,
    const float* __restrict__ x1, float* __restrict__ xp){
  int cc = blockIdx.x, f = threadIdx.x;
  float acc = 0.f;
  for (int n = 0; n < NN1; ++n) acc += s[n*128+cc] * x1[n*128+f];
  xp[cc*128+f] = acc;
}

// t[n][c] = sum_m adj[n][m]*s[m][c]
__global__ __launch_bounds__(128) void adj_s_kernel(const float* __restrict__ adj,
    const float* __restrict__ s, float* __restrict__ t){
  int n = blockIdx.x, c = threadIdx.x;
  float acc = 0.f;
  for (int m = 0; m < NN1; ++m){
    float a = adj[n*NN1+m];
    if (a != 0.f) acc += a * s[m*128+c];
  }
  t[n*128+c] = acc;
}

// adjp[c][d] = sum_n s[n][c]*t[n][d]
__global__ __launch_bounds__(128) void adjp_kernel(const float* __restrict__ s,
    const float* __restrict__ t, float* __restrict__ adjp){
  int cc = blockIdx.x, d = threadIdx.x;
  float acc = 0.f;
  for (int n = 0; n < NN1; ++n) acc += s[n*128+cc] * t[n*128+d];
  adjp[cc*128+d] = acc;
}

// per-row n: sum_m (adj[n][m] - s[n]·s[m])^2  -> linkpart[n]
__global__ __launch_bounds__(256) void link_kernel(const float* __restrict__ adj,
    const float* __restrict__ s, float* __restrict__ linkpart){
  __shared__ float sn[128]; __shared__ float red[256];
  int n = blockIdx.x, m = threadIdx.x;
  if (m < 128) sn[m] = s[n*128+m];
  __syncthreads();
  float dot = 0.f;
  const float* sm = s + m*128;
  for (int c = 0; c < 128; ++c) dot += sn[c]*sm[c];
  float v = adj[n*NN1+m] - dot;
  float part = block_sum<256>(v*v, red, m);
  if (m == 0) linkpart[n] = part;
}

// per row i of adjp: edge_out = (v==rowmax), cols[i] = first argmax, write ei2
__global__ __launch_bounds__(128) void binarize_kernel(const float* __restrict__ adjp,
    float* __restrict__ edge_out, float* __restrict__ ei2_out, int* __restrict__ cols){
  __shared__ float red[128]; __shared__ int redi[128];
  int i = blockIdx.x, j = threadIdx.x;
  float v = adjp[i*128+j];
  float mx = block_max<128>(v, red, j);
  edge_out[i*128+j] = (v == mx) ? 1.0f : 0.0f;
  int cand = (v == mx) ? j : (1 << 30);
  int cmin = block_min_int<128>(cand, redi, j);
  if (j == 0){
    cols[i] = cmin;
    ei2_out[i] = (float)i;
    ei2_out[128 + i] = (float)cmin;
  }
}

// deterministic mean aggregation for sage3: aggn3[d][f] = mean_{i: cols[i]==d} xp[i][f]
__global__ __launch_bounds__(128) void sage3_agg_kernel(const float* __restrict__ xp,
    const int* __restrict__ cols, float* __restrict__ aggn3){
  int d = blockIdx.x, f = threadIdx.x;
  float acc = 0.f, c = 0.f;
  for (int i = 0; i < NN2; ++i){
    if (cols[i] == d){ acc += xp[i*128+f]; c += 1.f; }   // uniform branch
  }
  aggn3[d*128+f] = acc / fmaxf(c, 1.f);
}

// nodes_out[n][o] = tanh(L2norm(aggn3[n]·wl3[o] + bl3[o] + xp[n]·wr3[o]))
__global__ __launch_bounds__(128) void sage3_out_kernel(const float* __restrict__ aggn3,
    const float* __restrict__ xp,
    const float* __restrict__ wl3, const float* __restrict__ bl3, const float* __restrict__ wr3,
    float* __restrict__ nodes_out)
{
  __shared__ float red[128];
  int n = blockIdx.x, k = threadIdx.x;
  float ag = aggn3[n*128+k];
  float xv = xp[n*128+k];
  float q0 = block_sum<128>(ag*wl3[k]     + xv*wr3[k],     red, k);
  float q1 = block_sum<128>(ag*wl3[128+k] + xv*wr3[128+k], red, k);
  if (k == 0){
    float p0 = q0 + bl3[0], p1 = q1 + bl3[1];
    float nm = fmaxf(sqrtf(p0*p0 + p1*p1), 1e-12f);
    nodes_out[n*2+0] = tanhf(p0/nm);
    nodes_out[n*2+1] = tanhf(p1/nm);
  }
}

// d_out[0..1]=x2, [2]=ll1+ll2, [3]=el1+el2
__global__ __launch_bounds__(256) void finalize_kernel(const float* __restrict__ linkpart,
    const float* __restrict__ entpart, float* __restrict__ d_out)
{
  __shared__ float red[256];
  int t = threadIdx.x;
  float ls = block_sum<256>(linkpart[t], red, t);
  float es = block_sum<256>(entpart[t], red, t);
  float v0 = 0.f, v1 = 0.f;
  if (t < 128){ v0 = d_out[4 + t*2 + 0]; v1 = d_out[4 + t*2 + 1]; }
  float s0 = block_sum<256>(v0, red, t);
  float s1 = block_sum<256>(v1, red, t);
  if (t == 0){
    d_out[0] = s0;
    d_out[1] = s1;
    d_out[2] = sqrtf(ls)/65536.0f + sqrtf(16256.0f)/16384.0f;  // ll1 + ll2(const)
    d_out[3] = es/256.0f;                                      // el1 + el2(=0 in f32)
  }
}

extern "C" void kernel_launch(void* const* d_in, const int* in_sizes, int n_in,
                              void* d_out_v, int out_size, void* d_ws, size_t ws_size,
                              hipStream_t stream)
{
  (void)in_sizes; (void)n_in; (void)out_size; (void)ws_size;
  const float* input = (const float*)d_in[0];
  const int*   ei    = (const int*)  d_in[1];
  const float* w1 = (const float*)d_in[2];  const float* b1 = (const float*)d_in[3];
  const float* w2 = (const float*)d_in[4];  const float* b2 = (const float*)d_in[5];
  const float* w3 = (const float*)d_in[6];  const float* b3 = (const float*)d_in[7];
  const float* w4 = (const float*)d_in[8];  const float* b4 = (const float*)d_in[9];
  const float* w5 = (const float*)d_in[10]; const float* b5 = (const float*)d_in[11];
  const float* s1wl = (const float*)d_in[12]; const float* s1bl = (const float*)d_in[13];
  const float* s1wr = (const float*)d_in[14];
  const float* s2wl = (const float*)d_in[15]; const float* s2bl = (const float*)d_in[16];
  const float* s2wr = (const float*)d_in[17];
  const float* s3wl = (const float*)d_in[18]; const float* s3bl = (const float*)d_in[19];
  const float* s3wr = (const float*)d_in[20];
  float* d_out = (float*)d_out_v;
  float* ws = (float*)d_ws;

  float* bufA = ws;                    // 2097152 (L1 out, L3 out)
  float* bufB = ws + 2097152;          // 1048576 (L2 out, L4 out)
  float* org  = ws + 3145728;          // 65536   (L5 out = node features)
  float* adj1 = ws + 3211264;          // 65536   (zeroed)
  float* cnt  = ws + 3276800;          // 256     (zeroed)
  float* aggn3= ws + 3277056;          // 16384
  float* aggn = ws + 3293568;          // 65536
  float* x1   = ws + 3359104;          // 32768
  float* s    = ws + 3391872;          // 32768
  float* t    = ws + 3424640;          // 32768
  float* xp   = ws + 3457408;          // 16384
  float* adjp = ws + 3473792;          // 16384
  int*   cols = (int*)(ws + 3490176);  // 128
  float* linkpart = ws + 3490304;      // 256
  float* entpart  = ws + 3490560;      // 256
  // total: 3490816 floats ~= 13.96 MB

  hipMemsetAsync(adj1, 0, (65536 + 256)*sizeof(float), stream);

  conv_relu_pool<5>  <<<dim3(32,32,8),  256, 0, stream>>>(input, w1, b1, bufA, 512, 512);
  conv_relu_pool<32> <<<dim3(16,16,16), 256, 0, stream>>>(bufA,  w2, b2, bufB, 256, 256);
  conv_relu_pool<64> <<<dim3(8,8,32),   256, 0, stream>>>(bufB,  w3, b3, bufA, 128, 128);
  conv_relu_pool<128><<<dim3(4,4,64),   256, 0, stream>>>(bufA,  w4, b4, bufB, 64, 64);
  conv_relu_pool<256><<<dim3(2,2,64),   256, 0, stream>>>(bufB,  w5, b5, org,  32, 32);

  build_adj_kernel<<<dim3(16),  256, 0, stream>>>(ei, adj1, cnt);
  agg_kernel      <<<dim3(256), 256, 0, stream>>>(adj1, cnt, org, aggn);
  sage12_kernel   <<<dim3(256), 128, 0, stream>>>(aggn, org, s1wl, s1bl, s1wr,
                                                  s2wl, s2bl, s2wr, x1, s, entpart);
  xp_kernel       <<<dim3(128), 128, 0, stream>>>(s, x1, xp);
  adj_s_kernel    <<<dim3(256), 128, 0, stream>>>(adj1, s, t);
  adjp_kernel     <<<dim3(128), 128, 0, stream>>>(s, t, adjp);
  link_kernel     <<<dim3(256), 256, 0, stream>>>(adj1, s, linkpart);
  binarize_kernel <<<dim3(128), 128, 0, stream>>>(adjp, d_out + 260, d_out + 16644, cols);
  sage3_agg_kernel<<<dim3(128), 128, 0, stream>>>(xp, cols, aggn3);
  sage3_out_kernel<<<dim3(128), 128, 0, stream>>>(aggn3, xp, s3wl, s3bl, s3wr, d_out + 4);
  finalize_kernel <<<dim3(1),   256, 0, stream>>>(linkpart, entpart, d_out);
}

// Round 2
// 588.533 us; speedup vs baseline: 1.5730x; 1.5730x over previous
//
#include <hip/hip_runtime.h>
#include <math.h>

#define N_EDGES 4096
#define NN1 256
#define NN2 128

// ---------------- reduction helpers ----------------
template<int NT>
__device__ inline float block_sum(float v, float* red, int t){
  red[t] = v; __syncthreads();
  #pragma unroll
  for (int st = NT/2; st > 0; st >>= 1){
    if (t < st) red[t] += red[t+st];
    __syncthreads();
  }
  float r = red[0]; __syncthreads();
  return r;
}
template<int NT>
__device__ inline float block_max(float v, float* red, int t){
  red[t] = v; __syncthreads();
  #pragma unroll
  for (int st = NT/2; st > 0; st >>= 1){
    if (t < st) red[t] = fmaxf(red[t], red[t+st]);
    __syncthreads();
  }
  float r = red[0]; __syncthreads();
  return r;
}
template<int NT>
__device__ inline int block_min_int(int v, int* red, int t){
  red[t] = v; __syncthreads();
  #pragma unroll
  for (int st = NT/2; st > 0; st >>= 1){
    if (t < st) red[t] = min(red[t], red[t+st]);
    __syncthreads();
  }
  int r = red[0]; __syncthreads();
  return r;
}

// ---------------- fused conv3x3(SAME) [+ReLU+maxpool if SPLITK==1] ----------------
// Block: 256 threads = 4 waves. Wave w handles couts [cg*16 + w*4, +4).
// Lane = 64 spatial positions (8x8 pooled region = 16x16 conv region).
// Each thread: 4 couts x 4 conv positions = 16 accumulators.
// grid.z = SPLITK * (COUT/16); split handles CIN/SPLITK input channels.
// SPLITK==1: out = pooled [COUT][H/2][W/2] with bias+relu+maxpool fused.
// SPLITK>1 : out = partial conv sums [split][COUT][H][W] (no bias/relu).
template<int CIN, int COUT, int SPLITK>
__global__ __launch_bounds__(256) void conv_krp(
    const float* __restrict__ in, const float* __restrict__ w,
    const float* __restrict__ bias, float* __restrict__ out,
    int H, int W)
{
  constexpr int CPB   = CIN / SPLITK;
  constexpr int CHUNK = (CPB < 8) ? CPB : 8;
  constexpr int CGRPS = COUT / 16;
  __shared__ float tile[CHUNK][18][18];
  __shared__ float wlds[16][CHUNK][9];

  const int split = blockIdx.z / CGRPS;
  const int cg    = blockIdx.z % CGRPS;
  const int tx0 = blockIdx.x * 8, ty0 = blockIdx.y * 8;
  const int lane = threadIdx.x & 63;
  const int wv   = threadIdx.x >> 6;
  const int px = lane & 7, py = lane >> 3;
  const int iy0 = 2*ty0 - 1, ix0 = 2*tx0 - 1;
  const int c_base = split * CPB;

  float acc[4][4];
  #pragma unroll
  for (int i=0;i<4;i++){ acc[i][0]=0.f; acc[i][1]=0.f; acc[i][2]=0.f; acc[i][3]=0.f; }

  for (int c0 = 0; c0 < CPB; c0 += CHUNK){
    __syncthreads();
    // stage input tile (CHUNK x 18 x 18)
    for (int e = threadIdx.x; e < CHUNK*324; e += 256){
      int c  = e / 324;
      int r  = e - c*324;
      int rr = r / 18;
      int cc = r - rr*18;
      int yy = iy0 + rr, xx = ix0 + cc;
      float v = 0.f;
      if ((unsigned)yy < (unsigned)H && (unsigned)xx < (unsigned)W)
        v = in[(size_t)(c_base + c0 + c)*H*W + (size_t)yy*W + xx];
      tile[c][rr][cc] = v;
    }
    // stage weights (16 couts x CHUNK x 9)
    for (int e = threadIdx.x; e < 16*CHUNK*9; e += 256){
      int co = e / (CHUNK*9);
      int r  = e - co*(CHUNK*9);
      int c  = r / 9;
      int k  = r - c*9;
      wlds[co][c][k] = w[((size_t)(cg*16 + co)*CIN + (c_base + c0 + c))*9 + k];
    }
    __syncthreads();

    const int ry = 2*py, rx = 2*px;
    #pragma unroll
    for (int c = 0; c < CHUNK; ++c){
      float p[4][4];
      #pragma unroll
      for (int i=0;i<4;i++){
        p[i][0]=tile[c][ry+i][rx+0]; p[i][1]=tile[c][ry+i][rx+1];
        p[i][2]=tile[c][ry+i][rx+2]; p[i][3]=tile[c][ry+i][rx+3];
      }
      #pragma unroll
      for (int co=0;co<4;co++){
        const float* wp = &wlds[wv*4+co][c][0];
        float w0=wp[0],w1=wp[1],w2=wp[2],w3=wp[3],w4=wp[4],w5=wp[5],w6=wp[6],w7=wp[7],w8=wp[8];
        acc[co][0] += w0*p[0][0]+w1*p[0][1]+w2*p[0][2] + w3*p[1][0]+w4*p[1][1]+w5*p[1][2] + w6*p[2][0]+w7*p[2][1]+w8*p[2][2];
        acc[co][1] += w0*p[0][1]+w1*p[0][2]+w2*p[0][3] + w3*p[1][1]+w4*p[1][2]+w5*p[1][3] + w6*p[2][1]+w7*p[2][2]+w8*p[2][3];
        acc[co][2] += w0*p[1][0]+w1*p[1][1]+w2*p[1][2] + w3*p[2][0]+w4*p[2][1]+w5*p[2][2] + w6*p[3][0]+w7*p[3][1]+w8*p[3][2];
        acc[co][3] += w0*p[1][1]+w1*p[1][2]+w2*p[1][3] + w3*p[2][1]+w4*p[2][2]+w5*p[2][3] + w6*p[3][1]+w7*p[3][2]+w8*p[3][3];
      }
    }
  }

  if (SPLITK == 1){
    const int OW = W >> 1, OH = H >> 1;
    #pragma unroll
    for (int co=0;co<4;co++){
      int cout = cg*16 + wv*4 + co;
      float m = fmaxf(fmaxf(acc[co][0],acc[co][1]),fmaxf(acc[co][2],acc[co][3])) + bias[cout];
      out[(size_t)cout*OH*OW + (size_t)(ty0+py)*OW + (tx0+px)] = fmaxf(m, 0.f);
    }
  } else {
    #pragma unroll
    for (int co=0;co<4;co++){
      int cout = cg*16 + wv*4 + co;
      float* pb = out + ((size_t)split*COUT + cout)*H*W;
      int y0 = 2*(ty0+py), x0 = 2*(tx0+px);
      pb[(size_t)y0*W + x0]       = acc[co][0];
      pb[(size_t)y0*W + x0+1]     = acc[co][1];
      pb[(size_t)(y0+1)*W + x0]   = acc[co][2];
      pb[(size_t)(y0+1)*W + x0+1] = acc[co][3];
    }
  }
}

// sum partial conv sums over splits, then bias + relu + maxpool2x2
template<int SPLITK>
__global__ __launch_bounds__(256) void reduce_pool(
    const float* __restrict__ pbuf, const float* __restrict__ bias,
    float* __restrict__ out, int COUT, int H, int W)
{
  int idx = blockIdx.x*256 + threadIdx.x;
  const int OW = W >> 1, OH = H >> 1;
  if (idx >= COUT*OH*OW) return;
  int px = idx % OW; int t = idx / OW; int py = t % OH; int cout = t / OH;
  size_t base = (size_t)cout*H*W + (size_t)(2*py)*W + 2*px;
  size_t sstr = (size_t)COUT*H*W;
  float s00=0.f, s01=0.f, s10=0.f, s11=0.f;
  #pragma unroll
  for (int s=0;s<SPLITK;s++){
    const float* pb = pbuf + s*sstr + base;
    s00 += pb[0]; s01 += pb[1]; s10 += pb[W]; s11 += pb[W+1];
  }
  float m = fmaxf(fmaxf(s00,s01),fmaxf(s10,s11)) + bias[cout];
  out[idx] = fmaxf(m, 0.f);
}

// ---------------- graph kernels ----------------
__global__ void build_adj_kernel(const int* __restrict__ ei, float* adj, float* cnt){
  int e = blockIdx.x*256 + threadIdx.x;
  if (e < N_EDGES){
    int s = ei[e], d = ei[N_EDGES + e];
    atomicAdd(&adj[s*NN1 + d], 1.0f);   // integer-valued -> order independent
    atomicAdd(&cnt[d], 1.0f);
  }
}

__global__ __launch_bounds__(256) void agg_kernel(const float* __restrict__ adj,
    const float* __restrict__ cnt, const float* __restrict__ org, float* __restrict__ aggn){
  int d = blockIdx.x, j = threadIdx.x;
  float acc = 0.f;
  for (int s = 0; s < NN1; ++s){
    float a = adj[s*NN1 + d];
    if (a != 0.f) acc += a * org[s*NN1 + j];
  }
  aggn[d*NN1 + j] = acc / fmaxf(cnt[d], 1.0f);
}

__global__ __launch_bounds__(128) void sage12_kernel(
    const float* __restrict__ aggn, const float* __restrict__ org,
    const float* __restrict__ wl1, const float* __restrict__ bl1, const float* __restrict__ wr1,
    const float* __restrict__ wl2, const float* __restrict__ bl2, const float* __restrict__ wr2,
    float* __restrict__ x1, float* __restrict__ s_out, float* __restrict__ entpart)
{
  __shared__ float sa[NN1], so[NN1], red[128];
  int n = blockIdx.x, c = threadIdx.x;
  for (int k = c; k < NN1; k += 128){ sa[k] = aggn[n*NN1+k]; so[k] = org[n*NN1+k]; }
  __syncthreads();
  float p1 = bl1[c], p2 = bl2[c];
  const float* wl1r = wl1 + c*NN1; const float* wr1r = wr1 + c*NN1;
  const float* wl2r = wl2 + c*NN1; const float* wr2r = wr2 + c*NN1;
  for (int k = 0; k < NN1; ++k){
    float av = sa[k], ov = so[k];
    p1 += av*wl1r[k] + ov*wr1r[k];
    p2 += av*wl2r[k] + ov*wr2r[k];
  }
  float n1s = block_sum<128>(p1*p1, red, c);
  x1[n*128 + c] = p1 / fmaxf(sqrtf(n1s), 1e-12f);
  float n2s = block_sum<128>(p2*p2, red, c);
  float p2n = p2 / fmaxf(sqrtf(n2s), 1e-12f);
  float mx = block_max<128>(p2n, red, c);
  float ev = expf(p2n - mx);
  float ssum = block_sum<128>(ev, red, c);
  float sv = ev / ssum;
  s_out[n*128 + c] = sv;
  float esum = block_sum<128>(-sv * logf(sv + 1e-15f), red, c);
  if (c == 0) entpart[n] = esum;
}

__global__ __launch_bounds__(128) void xp_kernel(const float* __restrict__ s,
    const float* __restrict__ x1, float* __restrict__ xp){
  int cc = blockIdx.x, f = threadIdx.x;
  float acc = 0.f;
  for (int n = 0; n < NN1; ++n) acc += s[n*128+cc] * x1[n*128+f];
  xp[cc*128+f] = acc;
}

__global__ __launch_bounds__(128) void adj_s_kernel(const float* __restrict__ adj,
    const float* __restrict__ s, float* __restrict__ t){
  int n = blockIdx.x, c = threadIdx.x;
  float acc = 0.f;
  for (int m = 0; m < NN1; ++m){
    float a = adj[n*NN1+m];
    if (a != 0.f) acc += a * s[m*128+c];
  }
  t[n*128+c] = acc;
}

__global__ __launch_bounds__(128) void adjp_kernel(const float* __restrict__ s,
    const float* __restrict__ t, float* __restrict__ adjp){
  int cc = blockIdx.x, d = threadIdx.x;
  float acc = 0.f;
  for (int n = 0; n < NN1; ++n) acc += s[n*128+cc] * t[n*128+d];
  adjp[cc*128+d] = acc;
}

__global__ __launch_bounds__(256) void link_kernel(const float* __restrict__ adj,
    const float* __restrict__ s, float* __restrict__ linkpart){
  __shared__ float sn[128]; __shared__ float red[256];
  int n = blockIdx.x, m = threadIdx.x;
  if (m < 128) sn[m] = s[n*128+m];
  __syncthreads();
  float dot = 0.f;
  const float* sm = s + m*128;
  for (int c = 0; c < 128; ++c) dot += sn[c]*sm[c];
  float v = adj[n*NN1+m] - dot;
  float part = block_sum<256>(v*v, red, m);
  if (m == 0) linkpart[n] = part;
}

__global__ __launch_bounds__(128) void binarize_kernel(const float* __restrict__ adjp,
    float* __restrict__ edge_out, float* __restrict__ ei2_out, int* __restrict__ cols){
  __shared__ float red[128]; __shared__ int redi[128];
  int i = blockIdx.x, j = threadIdx.x;
  float v = adjp[i*128+j];
  float mx = block_max<128>(v, red, j);
  edge_out[i*128+j] = (v == mx) ? 1.0f : 0.0f;
  int cand = (v == mx) ? j : (1 << 30);
  int cmin = block_min_int<128>(cand, redi, j);
  if (j == 0){
    cols[i] = cmin;
    ei2_out[i] = (float)i;
    ei2_out[128 + i] = (float)cmin;
  }
}

__global__ __launch_bounds__(128) void sage3_agg_kernel(const float* __restrict__ xp,
    const int* __restrict__ cols, float* __restrict__ aggn3){
  int d = blockIdx.x, f = threadIdx.x;
  float acc = 0.f, c = 0.f;
  for (int i = 0; i < NN2; ++i){
    if (cols[i] == d){ acc += xp[i*128+f]; c += 1.f; }
  }
  aggn3[d*128+f] = acc / fmaxf(c, 1.f);
}

__global__ __launch_bounds__(128) void sage3_out_kernel(const float* __restrict__ aggn3,
    const float* __restrict__ xp,
    const float* __restrict__ wl3, const float* __restrict__ bl3, const float* __restrict__ wr3,
    float* __restrict__ nodes_out)
{
  __shared__ float red[128];
  int n = blockIdx.x, k = threadIdx.x;
  float ag = aggn3[n*128+k];
  float xv = xp[n*128+k];
  float q0 = block_sum<128>(ag*wl3[k]     + xv*wr3[k],     red, k);
  float q1 = block_sum<128>(ag*wl3[128+k] + xv*wr3[128+k], red, k);
  if (k == 0){
    float p0 = q0 + bl3[0], p1 = q1 + bl3[1];
    float nm = fmaxf(sqrtf(p0*p0 + p1*p1), 1e-12f);
    nodes_out[n*2+0] = tanhf(p0/nm);
    nodes_out[n*2+1] = tanhf(p1/nm);
  }
}

__global__ __launch_bounds__(256) void finalize_kernel(const float* __restrict__ linkpart,
    const float* __restrict__ entpart, float* __restrict__ d_out)
{
  __shared__ float red[256];
  int t = threadIdx.x;
  float ls = block_sum<256>(linkpart[t], red, t);
  float es = block_sum<256>(entpart[t], red, t);
  float v0 = 0.f, v1 = 0.f;
  if (t < 128){ v0 = d_out[4 + t*2 + 0]; v1 = d_out[4 + t*2 + 1]; }
  float s0 = block_sum<256>(v0, red, t);
  float s1 = block_sum<256>(v1, red, t);
  if (t == 0){
    d_out[0] = s0;
    d_out[1] = s1;
    d_out[2] = sqrtf(ls)/65536.0f + sqrtf(16256.0f)/16384.0f;  // ll1 + ll2(const)
    d_out[3] = es/256.0f;                                      // el1 + el2(=0)
  }
}

extern "C" void kernel_launch(void* const* d_in, const int* in_sizes, int n_in,
                              void* d_out_v, int out_size, void* d_ws, size_t ws_size,
                              hipStream_t stream)
{
  (void)in_sizes; (void)n_in; (void)out_size; (void)ws_size;
  const float* input = (const float*)d_in[0];
  const int*   ei    = (const int*)  d_in[1];
  const float* w1 = (const float*)d_in[2];  const float* b1 = (const float*)d_in[3];
  const float* w2 = (const float*)d_in[4];  const float* b2 = (const float*)d_in[5];
  const float* w3 = (const float*)d_in[6];  const float* b3 = (const float*)d_in[7];
  const float* w4 = (const float*)d_in[8];  const float* b4 = (const float*)d_in[9];
  const float* w5 = (const float*)d_in[10]; const float* b5 = (const float*)d_in[11];
  const float* s1wl = (const float*)d_in[12]; const float* s1bl = (const float*)d_in[13];
  const float* s1wr = (const float*)d_in[14];
  const float* s2wl = (const float*)d_in[15]; const float* s2bl = (const float*)d_in[16];
  const float* s2wr = (const float*)d_in[17];
  const float* s3wl = (const float*)d_in[18]; const float* s3bl = (const float*)d_in[19];
  const float* s3wr = (const float*)d_in[20];
  float* d_out = (float*)d_out_v;
  float* ws = (float*)d_ws;

  // workspace layout (floats)
  float* bufA = ws;                         // 2,097,152
  float* bufB = ws + 2097152;               // 1,048,576
  float* pbuf = ws + 3145728;               // 2,097,152 (conv partials; graph scratch aliases after convs)
  float* org  = ws + 5242880;               // 65,536
  // total: 5,308,416 floats = 21.2 MB

  // graph scratch aliases the (dead after convs) pbuf region
  float* adj1     = pbuf;                   // 65,536
  float* cnt      = pbuf + 65536;           // 256
  float* aggn3    = pbuf + 65792;           // 16,384
  float* aggn     = pbuf + 82176;           // 65,536
  float* x1       = pbuf + 147712;          // 32,768
  float* s        = pbuf + 180480;          // 32,768
  float* t        = pbuf + 213248;          // 32,768
  float* xp       = pbuf + 246016;          // 16,384
  float* adjp     = pbuf + 262400;          // 16,384
  int*   cols     = (int*)(pbuf + 278784);  // 128
  float* linkpart = pbuf + 278912;          // 256
  float* entpart  = pbuf + 279168;          // 256

  // L1: 5->32 @512  (fused pool out: bufA 32x256x256)
  conv_krp<5,32,1>   <<<dim3(32,32,2),  256, 0, stream>>>(input, w1, b1, bufA, 512, 512);
  // L2: 32->64 @256 (fused pool out: bufB 64x128x128)
  conv_krp<32,64,1>  <<<dim3(16,16,4),  256, 0, stream>>>(bufA,  w2, b2, bufB, 256, 256);
  // L3: 64->128 @128 (fused pool out: bufA 128x64x64)
  conv_krp<64,128,1> <<<dim3(8,8,8),    256, 0, stream>>>(bufB,  w3, b3, bufA, 128, 128);
  // L4: 128->256 @64, split-K x2 -> partials, reduce -> bufB 256x32x32
  conv_krp<128,256,2><<<dim3(4,4,32),   256, 0, stream>>>(bufA,  w4, b4, pbuf, 64, 64);
  reduce_pool<2>     <<<dim3(1024),     256, 0, stream>>>(pbuf, b4, bufB, 256, 64, 64);
  // L5: 256->256 @32, split-K x8 -> partials, reduce -> org 256x16x16
  conv_krp<256,256,8><<<dim3(2,2,128),  256, 0, stream>>>(bufB,  w5, b5, pbuf, 32, 32);
  reduce_pool<8>     <<<dim3(256),      256, 0, stream>>>(pbuf, b5, org, 256, 32, 32);

  // graph tail (pbuf region now reusable as scratch)
  hipMemsetAsync(adj1, 0, (65536 + 256)*sizeof(float), stream);
  build_adj_kernel<<<dim3(16),  256, 0, stream>>>(ei, adj1, cnt);
  agg_kernel      <<<dim3(256), 256, 0, stream>>>(adj1, cnt, org, aggn);
  sage12_kernel   <<<dim3(256), 128, 0, stream>>>(aggn, org, s1wl, s1bl, s1wr,
                                                  s2wl, s2bl, s2wr, x1, s, entpart);
  xp_kernel       <<<dim3(128), 128, 0, stream>>>(s, x1, xp);
  adj_s_kernel    <<<dim3(256), 128, 0, stream>>>(adj1, s, t);
  adjp_kernel     <<<dim3(128), 128, 0, stream>>>(s, t, adjp);
  link_kernel     <<<dim3(256), 256, 0, stream>>>(adj1, s, linkpart);
  binarize_kernel <<<dim3(128), 128, 0, stream>>>(adjp, d_out + 260, d_out + 16644, cols);
  sage3_agg_kernel<<<dim3(128), 128, 0, stream>>>(xp, cols, aggn3);
  sage3_out_kernel<<<dim3(128), 128, 0, stream>>>(aggn3, xp, s3wl, s3bl, s3wr, d_out + 4);
  finalize_kernel <<<dim3(1),   256, 0, stream>>>(linkpart, entpart, d_out);
}